// Round 1
// baseline (165.794 us; speedup 1.0000x reference)
//
#include <hip/hip_runtime.h>

// RNNT (Transducer) alpha-recursion loss, forward only, mean reduction.
// Shapes fixed by setup_inputs(): B=4, T=512, U=100 (U+1=101), V=1024, fp32.
//
// alpha[t][u] = logaddexp(alpha[t-1][u] + blank[t-1][u],
//                         alpha[t][u-1] + emit[t][u-1]),  alpha[0][0]=0
// per_sample[b] = -alpha[T_b-1][U_b];  out = mean(per_sample)
//
// Strategy:
//  1) gather_kernel: wide, pulls blank (v=0) and emit (v=label) values out of
//     the 847 MB logits tensor into compact ANTI-DIAGONAL-major buffers
//     BL[b][d][u], EM[b][d][u] (d = t+u), ~2.4 MB total in static device mem.
//     At DP step s every lane reads row d = s-1 contiguously -> coalesced.
//  2) dp_kernel: 1 wave per batch element; lane l owns columns u=2l, 2l+1.
//     Odd column's left neighbor is in-register; only one __shfl rotate per
//     step on the carried chain. 8-deep static-unrolled prefetch hides L2/L3
//     latency (all indices compile-time -> registers, no scratch).
//  3) reduce_kernel: mean of the 4 per-sample values.

constexpr int B = 4, T = 512, U = 100, Up1 = 101, V = 1024;
constexpr int DIAGS = T + U;   // d = t+u in [0, 611]
constexpr int DSTR = 128;      // padded diag-row stride (floats)
constexpr int PF = 8;          // prefetch depth (DP steps)

// EM is stored shifted by +1 in u so that a float2 at even index gives
// (emit_needed_by_colA, emit_needed_by_colB):
//   EM[b][d][k] = emit[t = d-(k-1)][k-1]  for k in [1, U]
__device__ float g_BL[(size_t)B * DIAGS * DSTR];
__device__ float g_EM[(size_t)B * DIAGS * DSTR];
__device__ float g_ps[B];

__global__ __launch_bounds__(128) void gather_kernel(const float* __restrict__ logits,
                                                     const int* __restrict__ labels) {
  const int d = blockIdx.x;          // anti-diagonal index
  const int b = blockIdx.y;
  const int u = threadIdx.x;         // 0..127
  float* BL = g_BL + (size_t)(b * DIAGS + d) * DSTR;
  float* EM = g_EM + (size_t)(b * DIAGS + d) * DSTR;

  // blank: BL[d][u] = logits[b, t=d-u, u, 0]
  int t = d - u;
  if (u <= U && t >= 0 && t < T) {
    BL[u] = logits[(((size_t)b * T + t) * Up1 + u) * V];
  }
  // emit (shifted): EM[d][u] = logits[b, t2=d-u+1, u-1, label[u-1]]
  int t2 = d - u + 1;
  if (u >= 1 && u <= U && t2 >= 0 && t2 < T) {
    int lab = labels[b * U + (u - 1)];
    lab = lab < 0 ? 0 : (lab > V - 1 ? V - 1 : lab);
    EM[u] = logits[(((size_t)b * T + t2) * Up1 + (u - 1)) * V + lab];
  }
}

__device__ __forceinline__ float lse(float a, float b) {
  float m = fmaxf(a, b);
  float d = fabsf(a - b);
  return m + __logf(1.0f + __expf(-d));   // exact when one side is the -1e30 sentinel
}

__global__ __launch_bounds__(64) void dp_kernel(const int* __restrict__ logit_len,
                                                const int* __restrict__ label_len) {
  const int b = blockIdx.x;
  const int lane = threadIdx.x;      // 0..63
  constexpr float NEG = -1e30f;

  int Tb = logit_len[b]; Tb = Tb < 1 ? 1 : (Tb > T ? T : Tb);
  int Ub = label_len[b]; Ub = Ub < 1 ? 1 : (Ub > U ? U : Ub);

  const float2* BL = reinterpret_cast<const float2*>(g_BL + (size_t)b * DIAGS * DSTR);
  const float2* EM = reinterpret_cast<const float2*>(g_EM + (size_t)b * DIAGS * DSTR);
  constexpr int RS = DSTR / 2;       // float2 row stride

  float first = NEG;                 // column u = 2*lane   : alpha[t][2l]
  float second = NEG;                // column u = 2*lane+1 : alpha[t][2l+1]
  const int rot = (lane + 63) & 63;  // rotate-down-by-1 (lane 0 <- lane 63)

  // prefetch banks: step s consumes row s-1 (clamped to 0; masked at s=0)
  float2 pb[PF], pe[PF];
#pragma unroll
  for (int j = 0; j < PF; ++j) {
    int r = j - 1; if (r < 0) r = 0;
    pb[j] = BL[r * RS + lane];
    pe[j] = EM[r * RS + lane];
  }

  for (int s0 = 0; s0 < DIAGS; s0 += PF) {
    float2 nb[PF], ne[PF];
#pragma unroll
    for (int j = 0; j < PF; ++j) {
      int r = s0 + PF + j - 1;
      if (r < DIAGS) {
        nb[j] = BL[r * RS + lane];
        ne[j] = EM[r * RS + lane];
      } else {
        nb[j] = make_float2(NEG, NEG);
        ne[j] = make_float2(NEG, NEG);
      }
    }
#pragma unroll
    for (int j = 0; j < PF; ++j) {
      int s = s0 + j;
      if (s < DIAGS) {
        float pfB = __shfl(second, rot, 64);  // neighbor lane's colB, pre-update
        float oldA = first;                   // own colA, pre-update
        int tA = s - 2 * lane;
        // column A: u = 2*lane  (valid lanes 0..50)
        if (lane <= U / 2 && tA >= 0 && tA < T) {
          float up = (tA > 0) ? first + pb[j].x : NEG;
          float lf = (lane > 0) ? pfB + pe[j].x : NEG;
          float v = lse(up, lf);
          if ((tA | lane) == 0) v = 0.0f;     // alpha[0][0] = 0
          first = v;
          if (tA == Tb - 1 && 2 * lane == Ub) g_ps[b] = -v;
        }
        // column B: u = 2*lane+1 (valid lanes 0..49)
        int tB = tA - 1;
        if (lane <= (U - 2) / 2 && tB >= 0 && tB < T) {
          float up = (tB > 0) ? second + pb[j].y : NEG;
          float lf = oldA + pe[j].y;          // left col always exists (u>=1)
          float v = lse(up, lf);
          second = v;
          if (tB == Tb - 1 && 2 * lane + 1 == Ub) g_ps[b] = -v;
        }
      }
    }
#pragma unroll
    for (int j = 0; j < PF; ++j) { pb[j] = nb[j]; pe[j] = ne[j]; }
  }
}

__global__ void reduce_kernel(float* __restrict__ out) {
  float s = 0.0f;
  for (int i = 0; i < B; ++i) s += g_ps[i];
  out[0] = s * (1.0f / B);
}

extern "C" void kernel_launch(void* const* d_in, const int* in_sizes, int n_in,
                              void* d_out, int out_size, void* d_ws, size_t ws_size,
                              hipStream_t stream) {
  const float* logits    = (const float*)d_in[0];
  const int*   labels    = (const int*)d_in[1];
  const int*   logit_len = (const int*)d_in[2];
  const int*   label_len = (const int*)d_in[3];
  float* out = (float*)d_out;

  hipLaunchKernelGGL(gather_kernel, dim3(DIAGS, B), dim3(128), 0, stream, logits, labels);
  hipLaunchKernelGGL(dp_kernel, dim3(B), dim3(64), 0, stream, logit_len, label_len);
  hipLaunchKernelGGL(reduce_kernel, dim3(1), dim3(1), 0, stream, out);
}

// Round 2
// 101.271 us; speedup vs baseline: 1.6371x; 1.6371x over previous
//
#include <hip/hip_runtime.h>

// RNNT (Transducer) alpha-recursion loss, forward, mean reduction.
// B=4, T=512, U=100 (U+1=101 cols), V=1024, fp32.
//
// alpha[t][u] = lse(alpha[t-1][u] + blank[t-1][u], alpha[t][u-1] + emit[t][u-1])
// out = mean_b( -alpha[Tb-1][Ub] )
//
// Two kernels:
//  1) gather_kernel (wide): pull blank (v=0) and emit (v=label) from the 847MB
//     logits into anti-diagonal-major packed float4 rows, scaled by log2(e)
//     (DP runs in log2 domain -> raw v_exp_f32/v_log_f32, no ln<->log2 muls).
//     PK[b][r][l] = (blank[r-2l][2l], blank[r-2l-1][2l+1],
//                    emit[r-2l+1][2l-1], emit[r-2l][2l])   -- all on diag r.
//     Rows r > Tb+Ub are never consumed -> skipped (halves gather on average).
//  2) dp_kernel: 1 wave per batch; lane l owns columns u=2l, 2l+1. Cross-lane
//     neighbor via DPP wave_shr:1 (one VALU op, ~8cy, vs ds_bpermute ~100cy).
//     8-deep static prefetch (float4/row/lane). Loss finished in-kernel via
//     device-scope atomic counter (last block reduces) -> no 3rd launch.

constexpr int B = 4, T = 512, U = 100, Up1 = 101, V = 1024;
constexpr int DIAGS = T + U;       // 612
constexpr int PF = 8;
constexpr float NEG = -1e30f;
constexpr float LOG2E = 1.44269504088896340736f;
constexpr float LN2 = 0.69314718055994530942f;

__device__ float4 g_PK[(size_t)B * DIAGS * 64];
__device__ float g_ps[B];
__device__ int g_ctr = 0;

__device__ __forceinline__ int clampi(int x, int lo, int hi) {
  return x < lo ? lo : (x > hi ? hi : x);
}

__global__ __launch_bounds__(256) void gather_kernel(const float* __restrict__ logits,
                                                     const int* __restrict__ labels,
                                                     const int* __restrict__ logit_len,
                                                     const int* __restrict__ label_len) {
  const int b = blockIdx.y;
  const int r = blockIdx.x * 4 + (threadIdx.x >> 6);   // anti-diagonal row
  const int l = threadIdx.x & 63;                      // DP lane slot
  const int Tb = clampi(logit_len[b], 1, T);
  const int Ub = clampi(label_len[b], 1, U);
  if (r > Tb + Ub) return;                             // never consumed

  const float* lg = logits + (size_t)b * T * Up1 * V;
  const int u0 = 2 * l, u1 = u0 + 1;
  float4 v;
  v.x = v.y = v.z = v.w = NEG;

  int tx = r - u0;                                     // blank[tx][u0]
  if (u0 <= U && tx >= 0 && tx < T)
    v.x = LOG2E * lg[((size_t)tx * Up1 + u0) * V];
  int ty = r - u1;                                     // blank[ty][u1]
  if (u1 <= U && ty >= 0 && ty < T)
    v.y = LOG2E * lg[((size_t)ty * Up1 + u1) * V];
  int tz = r - u0 + 1;                                 // emit[tz][u0-1]
  if (u0 >= 1 && u0 <= U && tz >= 0 && tz < T) {
    int lab = clampi(labels[b * U + (u0 - 1)], 0, V - 1);
    v.z = LOG2E * lg[((size_t)tz * Up1 + (u0 - 1)) * V + lab];
  }
  int tw = r - u0;                                     // emit[tw][u0]
  if (u0 < U && tw >= 0 && tw < T) {
    int lab = clampi(labels[b * U + u0], 0, V - 1);
    v.w = LOG2E * lg[((size_t)tw * Up1 + u0) * V + lab];
  }
  g_PK[((size_t)b * DIAGS + r) * 64 + l] = v;
}

__device__ __forceinline__ float fexp2(float x) {
  float r; asm("v_exp_f32 %0, %1" : "=v"(r) : "v"(x)); return r;
}
__device__ __forceinline__ float flog2(float x) {
  float r; asm("v_log_f32 %0, %1" : "=v"(r) : "v"(x)); return r;
}
// log2-domain logaddexp: max(a,b) + log2(1 + 2^(-|a-b|))
__device__ __forceinline__ float lse2(float a, float b) {
  float m = fmaxf(a, b);
  float d = a - b;
  float nd = fminf(d, -d);        // -|a-b|
  return m + flog2(1.0f + fexp2(nd));
}
// whole-wave shift: lane l receives lane l-1 (lane 0 keeps own value; unused)
__device__ __forceinline__ float wave_shr1(float x) {
  int xi = __builtin_bit_cast(int, x);
  int r = __builtin_amdgcn_update_dpp(xi, xi, 0x138 /*WF_SR1*/, 0xF, 0xF, false);
  return __builtin_bit_cast(float, r);
}

__global__ __launch_bounds__(64) void dp_kernel(const int* __restrict__ logit_len,
                                                const int* __restrict__ label_len,
                                                float* __restrict__ out) {
  const int b = blockIdx.x;
  const int lane = threadIdx.x;
  const int Tb = clampi(logit_len[b], 1, T);
  const int Ub = clampi(label_len[b], 1, U);
  const int smax = Tb - 1 + Ub;    // diagonal of the answer cell

  const float4* PK = g_PK + (size_t)b * DIAGS * 64;

  float first = NEG;               // alpha[.][2*lane]
  float second = NEG;              // alpha[.][2*lane+1]

  float4 p[PF], n[PF];
#pragma unroll
  for (int j = 0; j < PF; ++j) {
    int r = j - 1; if (r < 0) r = 0;   // step 0 row is don't-care (masked)
    p[j] = PK[r * 64 + lane];
  }

  for (int s0 = 0; s0 <= smax; s0 += PF) {
#pragma unroll
    for (int j = 0; j < PF; ++j) {
      int r = s0 + PF + j - 1;
      if (r < DIAGS) n[j] = PK[r * 64 + lane];
      else           n[j] = make_float4(NEG, NEG, NEG, NEG);
    }
#pragma unroll
    for (int j = 0; j < PF; ++j) {
      int s = s0 + j;
      if (s <= smax) {                       // wave-uniform branch
        float pfB = wave_shr1(second);       // neighbor's odd column, pre-update
        float oldA = first;
        int tA = s - 2 * lane;
        // column A: u = 2*lane (lanes 0..50)
        if (lane <= U / 2 && tA >= 0 && tA < T) {
          float up = (tA > 0) ? first + p[j].x : NEG;
          float lf = (lane > 0) ? pfB + p[j].z : NEG;
          float v = lse2(up, lf);
          if ((tA | lane) == 0) v = 0.0f;    // alpha[0][0] = 0
          first = v;
          if (tA == Tb - 1 && 2 * lane == Ub)
            __hip_atomic_store(&g_ps[b], v, __ATOMIC_RELEASE, __HIP_MEMORY_SCOPE_AGENT);
        }
        // column B: u = 2*lane+1 (lanes 0..49)
        int tB = tA - 1;
        if (lane <= (U - 2) / 2 && tB >= 0 && tB < T) {
          float up = (tB > 0) ? second + p[j].y : NEG;
          float lf = oldA + p[j].w;
          float v = lse2(up, lf);
          second = v;
          if (tB == Tb - 1 && 2 * lane + 1 == Ub)
            __hip_atomic_store(&g_ps[b], v, __ATOMIC_RELEASE, __HIP_MEMORY_SCOPE_AGENT);
        }
      }
    }
#pragma unroll
    for (int j = 0; j < PF; ++j) p[j] = n[j];
  }

  // last block to finish computes the mean (device-scope handshake)
  if (lane == 0) {
    int old = __hip_atomic_fetch_add(&g_ctr, 1, __ATOMIC_ACQ_REL, __HIP_MEMORY_SCOPE_AGENT);
    if (old == B - 1) {
      float s = 0.0f;
      for (int i = 0; i < B; ++i)
        s += __hip_atomic_load(&g_ps[i], __ATOMIC_ACQUIRE, __HIP_MEMORY_SCOPE_AGENT);
      out[0] = -s * (LN2 / B);
      __hip_atomic_store(&g_ctr, 0, __ATOMIC_RELAXED, __HIP_MEMORY_SCOPE_AGENT);
    }
  }
}

extern "C" void kernel_launch(void* const* d_in, const int* in_sizes, int n_in,
                              void* d_out, int out_size, void* d_ws, size_t ws_size,
                              hipStream_t stream) {
  const float* logits = (const float*)d_in[0];
  const int* labels = (const int*)d_in[1];
  const int* logit_len = (const int*)d_in[2];
  const int* label_len = (const int*)d_in[3];
  float* out = (float*)d_out;

  hipLaunchKernelGGL(gather_kernel, dim3(DIAGS / 4, B), dim3(256), 0, stream,
                     logits, labels, logit_len, label_len);
  hipLaunchKernelGGL(dp_kernel, dim3(B), dim3(64), 0, stream,
                     logit_len, label_len, out);
}

// Round 3
// 97.195 us; speedup vs baseline: 1.7058x; 1.0419x over previous
//
#include <hip/hip_runtime.h>

// RNNT (Transducer) alpha-recursion loss, forward, mean reduction.
// B=4, T=512, U=100 (U+1=101 cols), V=1024, fp32.
//
// alpha[t][u] = lse(alpha[t-1][u] + blank[t-1][u], alpha[t][u-1] + emit[t][u-1])
// out = mean_b( -alpha[Tb-1][Ub] )
//
//  1) gather_kernel (wide): pull blank (v=0) and emit (v=label) from the 847MB
//     logits into anti-diagonal-major packed float4 rows (log2-scaled).
//     RECTANGLE MASK: only cells with t <= Tb-1 and u <= Ub (blank) /
//     u <= Ub-1 (emit) can influence alpha[Tb-1][Ub]; everything else is
//     skipped (~4x fewer scattered loads than unmasked on random lengths).
//     Unwritten g_PK cells are garbage but provably never flow into valid
//     columns (column u only feeds u and u+1; row t only feeds t, t+1).
//  2) dp_kernel: 1 wave per batch; lane l owns columns u=2l, 2l+1. Cross-lane
//     neighbor via DPP wave_shr:1. 16-deep static prefetch (covers ~600cy
//     L3 latency of g_PK row reads; 8-deep stalled ~300cy/batch). Loss is
//     finished in-kernel via device-scope atomic counter (last block reduces).

constexpr int B = 4, T = 512, U = 100, Up1 = 101, V = 1024;
constexpr int DIAGS = T + U;       // 612
constexpr int PF = 16;
constexpr float NEG = -1e30f;
constexpr float LOG2E = 1.44269504088896340736f;
constexpr float LN2 = 0.69314718055994530942f;

__device__ float4 g_PK[(size_t)B * DIAGS * 64];
__device__ float g_ps[B];
__device__ int g_ctr = 0;

__device__ __forceinline__ int clampi(int x, int lo, int hi) {
  return x < lo ? lo : (x > hi ? hi : x);
}

__global__ __launch_bounds__(256) void gather_kernel(const float* __restrict__ logits,
                                                     const int* __restrict__ labels,
                                                     const int* __restrict__ logit_len,
                                                     const int* __restrict__ label_len) {
  const int b = blockIdx.y;
  const int r = blockIdx.x * 4 + (threadIdx.x >> 6);   // anti-diagonal row
  const int l = threadIdx.x & 63;                      // DP lane slot
  const int Tb = clampi(logit_len[b], 1, T);
  const int Ub = clampi(label_len[b], 1, U);
  if (r > Tb - 1 + Ub) return;                         // beyond answer diagonal

  const float* lg = logits + (size_t)b * T * Up1 * V;
  const int u0 = 2 * l, u1 = u0 + 1;
  float4 v;
  v.x = v.y = v.z = v.w = NEG;

  // blank needed only for t <= Tb-1, u <= Ub; emit only for t <= Tb-1, u <= Ub-1
  int tx = r - u0;                                     // blank[tx][u0]
  if (u0 <= Ub && tx >= 0 && tx <= Tb - 1)
    v.x = LOG2E * lg[((size_t)tx * Up1 + u0) * V];
  int ty = r - u1;                                     // blank[ty][u1]
  if (u1 <= Ub && ty >= 0 && ty <= Tb - 1)
    v.y = LOG2E * lg[((size_t)ty * Up1 + u1) * V];
  int tz = r - u0 + 1;                                 // emit[tz][u0-1]
  if (u0 >= 1 && u0 - 1 <= Ub - 1 && tz >= 0 && tz <= Tb - 1) {
    int lab = clampi(labels[b * U + (u0 - 1)], 0, V - 1);
    v.z = LOG2E * lg[((size_t)tz * Up1 + (u0 - 1)) * V + lab];
  }
  int tw = r - u0;                                     // emit[tw][u0]
  if (u0 <= Ub - 1 && tw >= 0 && tw <= Tb - 1) {
    int lab = clampi(labels[b * U + u0], 0, V - 1);
    v.w = LOG2E * lg[((size_t)tw * Up1 + u0) * V + lab];
  }
  g_PK[((size_t)b * DIAGS + r) * 64 + l] = v;
}

__device__ __forceinline__ float fexp2(float x) {
  float r; asm("v_exp_f32 %0, %1" : "=v"(r) : "v"(x)); return r;
}
__device__ __forceinline__ float flog2(float x) {
  float r; asm("v_log_f32 %0, %1" : "=v"(r) : "v"(x)); return r;
}
// log2-domain logaddexp: max(a,b) + log2(1 + 2^(-|a-b|))
__device__ __forceinline__ float lse2(float a, float b) {
  float m = fmaxf(a, b);
  float d = a - b;
  float nd = fminf(d, -d);        // -|a-b|
  return m + flog2(1.0f + fexp2(nd));
}
// whole-wave shift: lane l receives lane l-1 (lane 0 keeps own value; unused)
__device__ __forceinline__ float wave_shr1(float x) {
  int xi = __builtin_bit_cast(int, x);
  int r = __builtin_amdgcn_update_dpp(xi, xi, 0x138 /*WF_SR1*/, 0xF, 0xF, false);
  return __builtin_bit_cast(float, r);
}

__global__ __launch_bounds__(64) void dp_kernel(const int* __restrict__ logit_len,
                                                const int* __restrict__ label_len,
                                                float* __restrict__ out) {
  const int b = blockIdx.x;
  const int lane = threadIdx.x;
  const int Tb = clampi(logit_len[b], 1, T);
  const int Ub = clampi(label_len[b], 1, U);
  const int smax = Tb - 1 + Ub;    // diagonal of the answer cell

  const float4* PK = g_PK + (size_t)b * DIAGS * 64;

  float first = NEG;               // alpha[.][2*lane]
  float second = NEG;              // alpha[.][2*lane+1]

  float4 p[PF], n[PF];
#pragma unroll
  for (int j = 0; j < PF; ++j) {
    int r = j - 1; if (r < 0) r = 0;   // step 0 row is don't-care (masked)
    p[j] = PK[r * 64 + lane];
  }

  for (int s0 = 0; s0 <= smax; s0 += PF) {
#pragma unroll
    for (int j = 0; j < PF; ++j) {
      int r = s0 + PF + j - 1;
      if (r < DIAGS) n[j] = PK[r * 64 + lane];
      else           n[j] = make_float4(NEG, NEG, NEG, NEG);
    }
#pragma unroll
    for (int j = 0; j < PF; ++j) {
      int s = s0 + j;
      if (s <= smax) {                       // wave-uniform branch
        float pfB = wave_shr1(second);       // neighbor's odd column, pre-update
        float oldA = first;
        int tA = s - 2 * lane;
        // column A: u = 2*lane (lanes 0..50)
        if (lane <= U / 2 && tA >= 0 && tA < T) {
          float up = (tA > 0) ? first + p[j].x : NEG;
          float lf = (lane > 0) ? pfB + p[j].z : NEG;
          float v = lse2(up, lf);
          if ((tA | lane) == 0) v = 0.0f;    // alpha[0][0] = 0
          first = v;
          if (tA == Tb - 1 && 2 * lane == Ub)
            __hip_atomic_store(&g_ps[b], v, __ATOMIC_RELEASE, __HIP_MEMORY_SCOPE_AGENT);
        }
        // column B: u = 2*lane+1 (lanes 0..49)
        int tB = tA - 1;
        if (lane <= (U - 2) / 2 && tB >= 0 && tB < T) {
          float up = (tB > 0) ? second + p[j].y : NEG;
          float lf = oldA + p[j].w;
          float v = lse2(up, lf);
          second = v;
          if (tB == Tb - 1 && 2 * lane + 1 == Ub)
            __hip_atomic_store(&g_ps[b], v, __ATOMIC_RELEASE, __HIP_MEMORY_SCOPE_AGENT);
        }
      }
    }
#pragma unroll
    for (int j = 0; j < PF; ++j) p[j] = n[j];
  }

  // last block to finish computes the mean (device-scope handshake)
  if (lane == 0) {
    int old = __hip_atomic_fetch_add(&g_ctr, 1, __ATOMIC_ACQ_REL, __HIP_MEMORY_SCOPE_AGENT);
    if (old == B - 1) {
      float s = 0.0f;
      for (int i = 0; i < B; ++i)
        s += __hip_atomic_load(&g_ps[i], __ATOMIC_ACQUIRE, __HIP_MEMORY_SCOPE_AGENT);
      out[0] = -s * (LN2 / B);
      __hip_atomic_store(&g_ctr, 0, __ATOMIC_RELAXED, __HIP_MEMORY_SCOPE_AGENT);
    }
  }
}

extern "C" void kernel_launch(void* const* d_in, const int* in_sizes, int n_in,
                              void* d_out, int out_size, void* d_ws, size_t ws_size,
                              hipStream_t stream) {
  const float* logits = (const float*)d_in[0];
  const int* labels = (const int*)d_in[1];
  const int* logit_len = (const int*)d_in[2];
  const int* label_len = (const int*)d_in[3];
  float* out = (float*)d_out;

  hipLaunchKernelGGL(gather_kernel, dim3(DIAGS / 4, B), dim3(256), 0, stream,
                     logits, labels, logit_len, label_len);
  hipLaunchKernelGGL(dp_kernel, dim3(B), dim3(64), 0, stream,
                     logit_len, label_len, out);
}